// Round 11
// baseline (180.080 us; speedup 1.0000x reference)
//
#include <hip/hip_runtime.h>
#include <hip/hip_bf16.h>

#define N_NODES 100000
#define N_EDGES 800000
#define HIDDEN 128
#define N_TILES 1563            // ceil(100000 / 64)
#define PC_GRID 512             // fallback persistent-GEMM grid (2 blocks/CU)

typedef short frag_ab __attribute__((ext_vector_type(8)));   // 8 x bf16
typedef float frag_cd __attribute__((ext_vector_type(4)));   // 4 x f32

// round-to-nearest-even fp32 -> bf16 (scalar)
__device__ inline unsigned short f2b(float f) {
    union { float f; unsigned u; } x; x.f = f;
    return (unsigned short)((x.u + 0x7fffu + ((x.u >> 16) & 1u)) >> 16);
}

// packed pair fp32 -> bf16x2 (v_cvt_pk_bf16_f32 on gfx950)
__device__ inline unsigned pk2(float x, float y) {
    union { __hip_bfloat162 h; unsigned u; } c;
    c.h = __float22bfloat162_rn(make_float2(x, y));
    return c.u;
}

// ---------------------------------------------------------------------------
// Kernel 0: transpose+convert W1 (256x128 fp32) -> Bt[256][128] bf16, k-contig.
// ---------------------------------------------------------------------------
__global__ __launch_bounds__(256) void transpose_w1(
    const float* __restrict__ W1, unsigned short* __restrict__ Bt)
{
    const int t  = threadIdx.x;
    const int nc = blockIdx.x * 4 + (t >> 6);
    const int k2 = (t & 63) * 2;
    const int col  = nc & 127;
    const int roff = (nc >= 128) ? 128 : 0;
    float f0 = W1[(size_t)(roff + k2)     * HIDDEN + col];
    float f1 = W1[(size_t)(roff + k2 + 1) * HIDDEN + col];
    *(unsigned*)(Bt + (size_t)nc * HIDDEN + k2) = (unsigned)f2b(f0) | ((unsigned)f2b(f1) << 16);
}

// ---------------------------------------------------------------------------
// Kernel 0b (new, R11): rewrite z into MFMA-A-FRAGMENT order, bf16.
// Chunk (panel p, q, lane l) of 16 B = z[p*16 + (l&15)][q*32 + (l>>4)*8 ..+7]
// stored at zf[((p*4)+q)*64 + l]. A wave's A-frag load then becomes
// lane-contiguous (1 KB per instruction) — fixes R8's address-divergence
// failure while keeping its barrier-free main loop.
// Block: 4 panels (64 z-rows). Coalesced read -> LDS (known-good R10 staging
// geometry) -> coalesced 16-B chunk writes (1 KB segments per wave).
// ---------------------------------------------------------------------------
__global__ __launch_bounds__(256) void zswz(
    const float* __restrict__ z, uint4* __restrict__ zf)
{
    __shared__ unsigned short s[64 * 136];
    const int t = threadIdx.x;
    const int r0 = blockIdx.x * 64;

    #pragma unroll
    for (int i = 0; i < 8; ++i) {
        int f4 = i * 256 + t;
        int m = f4 >> 5;
        int c4 = f4 & 31;
        int mr = r0 + m; if (mr >= N_NODES) mr = N_NODES - 1;
        float4 v = ((const float4*)z)[(size_t)mr * 32 + c4];
        uint2 p;
        p.x = pk2(v.x, v.y);
        p.y = pk2(v.z, v.w);
        *(uint2*)&s[m * 136 + c4 * 4] = p;
    }
    __syncthreads();

    const int q = t >> 6;        // this thread's k-quad
    const int l = t & 63;        // output lane id
    const int g = l >> 4;
    const int lc = l & 15;
    #pragma unroll
    for (int i = 0; i < 4; ++i) {            // panel within block
        int row = i * 16 + lc;
        uint4 chunk = *(const uint4*)&s[row * 136 + q * 32 + g * 8];
        zf[((size_t)(blockIdx.x * 4 + i) * 4 + q) * 64 + l] = chunk;
    }
}

// ---------------------------------------------------------------------------
// Kernel 1 v2 (R11): GEMM from fragment-ordered zf. Per wave: 16 perfectly
// coalesced 16-B A-frag loads (LLC-hot: zf written by zswz immediately
// before), register B, 64 MFMA, ONE barrier (C assembly), coalesced store.
// No A-staging LDS, no prefetch regs (VGPR ~ acc64+b64+a16).
// ---------------------------------------------------------------------------
#define CS_STRIDE 264

__global__ __launch_bounds__(256) void precompute_uv_mfma_v2(
    const uint4* __restrict__ zf, const unsigned short* __restrict__ Bt,
    const float* __restrict__ b1, unsigned short* __restrict__ UV)
{
    __shared__ unsigned short smem[64 * CS_STRIDE];   // C only
    const int t = threadIdx.x;
    const int lane = t & 63;
    const int w = t >> 6;
    const int wn = w * 64;
    const int g  = lane >> 4;
    const int lc = lane & 15;
    const int tile = blockIdx.x;

    // --- B fragments + bias ---
    frag_ab b[4][4];
    float bias[4];
    #pragma unroll
    for (int nt = 0; nt < 4; ++nt) {
        int nc = wn + nt * 16 + lc;
        bias[nt] = (nc < HIDDEN) ? b1[nc] : 0.f;
        const unsigned short* brow = Bt + (size_t)nc * HIDDEN;
        #pragma unroll
        for (int q = 0; q < 4; ++q)
            b[nt][q] = *(const frag_ab*)(brow + q * 32 + g * 8);
    }

    frag_cd acc[4][4];
    #pragma unroll
    for (int mt = 0; mt < 4; ++mt)
        #pragma unroll
        for (int nt = 0; nt < 4; ++nt)
            acc[mt][nt] = (frag_cd){0.f, 0.f, 0.f, 0.f};

    // --- K loop: per q, 4 lane-contiguous A-frag loads + 16 MFMA ---
    const frag_ab* zfa = (const frag_ab*)zf;
    #pragma unroll
    for (int q = 0; q < 4; ++q) {
        frag_ab a[4];
        #pragma unroll
        for (int mt = 0; mt < 4; ++mt)
            a[mt] = zfa[((size_t)(tile * 4 + mt) * 4 + q) * 64 + lane];
        #pragma unroll
        for (int mt = 0; mt < 4; ++mt)
            #pragma unroll
            for (int nt = 0; nt < 4; ++nt)
                acc[mt][nt] = __builtin_amdgcn_mfma_f32_16x16x32_bf16(
                    a[mt], b[nt][q], acc[mt][nt], 0, 0, 0);
    }

    // --- epilogue: acc -> smem (C layout col=lane&15, row=(lane>>4)*4+reg) ---
    #pragma unroll
    for (int nt = 0; nt < 4; ++nt) {
        int nc = wn + nt * 16 + lc;
        #pragma unroll
        for (int mt = 0; mt < 4; ++mt)
            #pragma unroll
            for (int r = 0; r < 4; ++r)
                smem[(mt * 16 + g * 4 + r) * CS_STRIDE + nc] =
                    f2b(acc[mt][nt][r] + bias[nt]);
    }
    __syncthreads();   // the ONLY barrier

    const int m0 = tile * 64;
    #pragma unroll
    for (int i = 0; i < 8; ++i) {
        int f = i * 256 + t;
        int m = f >> 5;
        int c16 = f & 31;
        if (m0 + m < N_NODES) {
            uint4 val = *(const uint4*)&smem[m * CS_STRIDE + c16 * 8];
            *(uint4*)&UV[(size_t)(m0 + m) * 256 + c16 * 8] = val;
        }
    }
}

// ---------------------------------------------------------------------------
// Kernel 1 FALLBACK (R10 banked config, used when ws_size can't fit zf).
// ---------------------------------------------------------------------------
#define AS_STRIDE 136

__global__ __launch_bounds__(256) void precompute_uv_mfma(
    const float* __restrict__ z, const unsigned short* __restrict__ Bt,
    const float* __restrict__ b1, unsigned short* __restrict__ UV)
{
    __shared__ unsigned short smem[64 * CS_STRIDE];
    const int t = threadIdx.x;
    const int lane = t & 63;
    const int w = t >> 6;
    const int wn = w * 64;
    const int g  = lane >> 4;
    const int lc = lane & 15;

    frag_ab b[4][4];
    float bias[4];
    #pragma unroll
    for (int nt = 0; nt < 4; ++nt) {
        int nc = wn + nt * 16 + lc;
        bias[nt] = (nc < HIDDEN) ? b1[nc] : 0.f;
        const unsigned short* brow = Bt + (size_t)nc * HIDDEN;
        #pragma unroll
        for (int q = 0; q < 4; ++q)
            b[nt][q] = *(const frag_ab*)(brow + q * 32 + g * 8);
    }

    int tile = blockIdx.x;
    uint2 pf[8];
    #pragma unroll
    for (int i = 0; i < 8; ++i) {
        int f4 = i * 256 + t;
        int m = tile * 64 + (f4 >> 5);
        if (m >= N_NODES) m = N_NODES - 1;
        float4 v = ((const float4*)z)[(size_t)m * 32 + (f4 & 31)];
        pf[i].x = pk2(v.x, v.y);
        pf[i].y = pk2(v.z, v.w);
    }

    while (true) {
        #pragma unroll
        for (int i = 0; i < 8; ++i) {
            int f4 = i * 256 + t;
            *(uint2*)&smem[(f4 >> 5) * AS_STRIDE + (f4 & 31) * 4] = pf[i];
        }
        __syncthreads();

        const int next = tile + PC_GRID;
        const bool have_next = (next < N_TILES);
        if (have_next) {
            #pragma unroll
            for (int i = 0; i < 8; ++i) {
                int f4 = i * 256 + t;
                int m = next * 64 + (f4 >> 5);
                if (m >= N_NODES) m = N_NODES - 1;
                float4 v = ((const float4*)z)[(size_t)m * 32 + (f4 & 31)];
                pf[i].x = pk2(v.x, v.y);
                pf[i].y = pk2(v.z, v.w);
            }
        }

        frag_cd acc[4][4];
        #pragma unroll
        for (int mt = 0; mt < 4; ++mt)
            #pragma unroll
            for (int nt = 0; nt < 4; ++nt)
                acc[mt][nt] = (frag_cd){0.f, 0.f, 0.f, 0.f};
        #pragma unroll
        for (int q = 0; q < 4; ++q) {
            frag_ab a[4];
            #pragma unroll
            for (int mt = 0; mt < 4; ++mt)
                a[mt] = *(const frag_ab*)&smem[(mt * 16 + lc) * AS_STRIDE + q * 32 + g * 8];
            #pragma unroll
            for (int mt = 0; mt < 4; ++mt)
                #pragma unroll
                for (int nt = 0; nt < 4; ++nt)
                    acc[mt][nt] = __builtin_amdgcn_mfma_f32_16x16x32_bf16(
                        a[mt], b[nt][q], acc[mt][nt], 0, 0, 0);
        }
        __syncthreads();

        #pragma unroll
        for (int nt = 0; nt < 4; ++nt) {
            int nc = wn + nt * 16 + lc;
            #pragma unroll
            for (int mt = 0; mt < 4; ++mt)
                #pragma unroll
                for (int r = 0; r < 4; ++r)
                    smem[(mt * 16 + g * 4 + r) * CS_STRIDE + nc] =
                        f2b(acc[mt][nt][r] + bias[nt]);
        }
        __syncthreads();

        const int m0 = tile * 64;
        #pragma unroll
        for (int i = 0; i < 8; ++i) {
            int f = i * 256 + t;
            int m = f >> 5;
            int c16 = f & 31;
            if (m0 + m < N_NODES) {
                uint4 val = *(const uint4*)&smem[m * CS_STRIDE + c16 * 8];
                *(uint4*)&UV[(size_t)(m0 + m) * 256 + c16 * 8] = val;
            }
        }
        if (!have_next) break;
        __syncthreads();
        tile = next;
    }
}

// ---------------------------------------------------------------------------
// Kernel 2: per-edge score = relu(U[src] + V[dst]) . W2 + b2
// UNCHANGED — at the L2-miss-path gather ceiling (~3.5 TB/s).
// ---------------------------------------------------------------------------
__device__ inline float2 bf2(unsigned u) {
    union { unsigned i; float f; } lo, hi;
    lo.i = u << 16;
    hi.i = u & 0xffff0000u;
    return make_float2(lo.f, hi.f);
}

__device__ inline float2 rfma2(unsigned u, unsigned v, float2 w, float2 acc) {
    float2 uf = bf2(u), vf = bf2(v);
    float2 s = make_float2(uf.x + vf.x, uf.y + vf.y);
    s.x = fmaxf(s.x, 0.f); s.y = fmaxf(s.y, 0.f);
    acc.x = __builtin_fmaf(s.x, w.x, acc.x);
    acc.y = __builtin_fmaf(s.y, w.y, acc.y);
    return acc;
}

__global__ __launch_bounds__(256) void edge_score(
    const int* __restrict__ ei, const unsigned short* __restrict__ UV,
    const float* __restrict__ W2, const float* __restrict__ B2,
    float* __restrict__ out)
{
    const int t = threadIdx.x;
    const int g = t & 7;
    const int slot = t >> 3;
    const int e0 = blockIdx.x * 64 + slot;
    const int e1 = e0 + 32;

    const float4* W24 = (const float4*)W2;
    const float4 w0 = W24[g * 4 + 0];
    const float4 w1 = W24[g * 4 + 1];
    const float4 w2 = W24[g * 4 + 2];
    const float4 w3 = W24[g * 4 + 3];

    const int s0 = ei[e0];
    const int d0 = ei[N_EDGES + e0];
    const int s1 = ei[e1];
    const int d1 = ei[N_EDGES + e1];

    const uint4* u0p = (const uint4*)(UV + (size_t)s0 * 256) + g * 2;
    const uint4* v0p = (const uint4*)(UV + (size_t)d0 * 256 + 128) + g * 2;
    const uint4* u1p = (const uint4*)(UV + (size_t)s1 * 256) + g * 2;
    const uint4* v1p = (const uint4*)(UV + (size_t)d1 * 256 + 128) + g * 2;
    const uint4 ua0 = u0p[0], ub0 = u0p[1];
    const uint4 va0 = v0p[0], vb0 = v0p[1];
    const uint4 ua1 = u1p[0], ub1 = u1p[1];
    const uint4 va1 = v1p[0], vb1 = v1p[1];

    float2 A = make_float2(0.f, 0.f), B = make_float2(0.f, 0.f);
    A = rfma2(ua0.x, va0.x, make_float2(w0.x, w0.y), A);
    A = rfma2(ua0.y, va0.y, make_float2(w0.z, w0.w), A);
    A = rfma2(ua0.z, va0.z, make_float2(w1.x, w1.y), A);
    A = rfma2(ua0.w, va0.w, make_float2(w1.z, w1.w), A);
    A = rfma2(ub0.x, vb0.x, make_float2(w2.x, w2.y), A);
    A = rfma2(ub0.y, vb0.y, make_float2(w2.z, w2.w), A);
    A = rfma2(ub0.z, vb0.z, make_float2(w3.x, w3.y), A);
    A = rfma2(ub0.w, vb0.w, make_float2(w3.z, w3.w), A);

    B = rfma2(ua1.x, va1.x, make_float2(w0.x, w0.y), B);
    B = rfma2(ua1.y, va1.y, make_float2(w0.z, w0.w), B);
    B = rfma2(ua1.z, va1.z, make_float2(w1.x, w1.y), B);
    B = rfma2(ua1.w, va1.w, make_float2(w1.z, w1.w), B);
    B = rfma2(ub1.x, vb1.x, make_float2(w2.x, w2.y), B);
    B = rfma2(ub1.y, vb1.y, make_float2(w2.z, w2.w), B);
    B = rfma2(ub1.z, vb1.z, make_float2(w3.x, w3.y), B);
    B = rfma2(ub1.w, vb1.w, make_float2(w3.z, w3.w), B);

    float sa = A.x + A.y;
    float sb = B.x + B.y;
    sa += __shfl_xor(sa, 1, 8);
    sa += __shfl_xor(sa, 2, 8);
    sa += __shfl_xor(sa, 4, 8);
    sb += __shfl_xor(sb, 1, 8);
    sb += __shfl_xor(sb, 2, 8);
    sb += __shfl_xor(sb, 4, 8);

    if (g == 0) {
        float bb = B2[0];
        out[e0] = sa + bb;
        out[e1] = sb + bb;
    }
}

extern "C" void kernel_launch(void* const* d_in, const int* in_sizes, int n_in,
                              void* d_out, int out_size, void* d_ws, size_t ws_size,
                              hipStream_t stream) {
    const float* z  = (const float*)d_in[0];
    const int*   ei = (const int*)d_in[1];
    const float* W1 = (const float*)d_in[2];
    const float* b1 = (const float*)d_in[3];
    const float* W2 = (const float*)d_in[4];
    const float* b2 = (const float*)d_in[5];
    float* out = (float*)d_out;

    unsigned short* UV = (unsigned short*)d_ws;                  // 51.2 MB
    unsigned short* Bt = UV + (size_t)N_NODES * 256;             // 64 KB
    uint4* zf = (uint4*)(Bt + (size_t)256 * HIDDEN);             // 25.6 MB

    const size_t need = (size_t)N_NODES * 256 * 2      // UV
                      + (size_t)256 * HIDDEN * 2       // Bt
                      + (size_t)N_TILES * 4 * 4 * 64 * 16;  // zf

    transpose_w1<<<64, 256, 0, stream>>>(W1, Bt);
    if (ws_size >= need) {
        zswz<<<N_TILES, 256, 0, stream>>>(z, zf);
        precompute_uv_mfma_v2<<<N_TILES, 256, 0, stream>>>(zf, Bt, b1, UV);
    } else {
        precompute_uv_mfma<<<PC_GRID, 256, 0, stream>>>(z, Bt, b1, UV);
    }
    edge_score<<<N_EDGES / 64, 256, 0, stream>>>(ei, UV, W2, b2, out);
}

// Round 12
// 165.004 us; speedup vs baseline: 1.0914x; 1.0914x over previous
//
#include <hip/hip_runtime.h>
#include <hip/hip_bf16.h>

#define N_NODES 100000
#define N_EDGES 800000
#define HIDDEN 128
#define N_TILES 1563            // ceil(100000 / 64)
#define PC_GRID 512             // 2 blocks/CU residency (VGPR >128 => 8 waves/CU);
                                // ~3 tiles/block, no ragged second dispatch pass.

typedef short frag_ab __attribute__((ext_vector_type(8)));   // 8 x bf16
typedef float frag_cd __attribute__((ext_vector_type(4)));   // 4 x f32

// round-to-nearest-even fp32 -> bf16 (scalar)
__device__ inline unsigned short f2b(float f) {
    union { float f; unsigned u; } x; x.f = f;
    return (unsigned short)((x.u + 0x7fffu + ((x.u >> 16) & 1u)) >> 16);
}

// packed pair fp32 -> bf16x2 (v_cvt_pk_bf16_f32 on gfx950)
__device__ inline unsigned pk2(float x, float y) {
    union { __hip_bfloat162 h; unsigned u; } c;
    c.h = __float22bfloat162_rn(make_float2(x, y));
    return c.u;
}

// ---------------------------------------------------------------------------
// Kernel 0: transpose+convert W1 (256x128 fp32) -> Bt[256][128] bf16, k-contig.
// ---------------------------------------------------------------------------
__global__ __launch_bounds__(256) void transpose_w1(
    const float* __restrict__ W1, unsigned short* __restrict__ Bt)
{
    const int t  = threadIdx.x;
    const int nc = blockIdx.x * 4 + (t >> 6);
    const int k2 = (t & 63) * 2;
    const int col  = nc & 127;
    const int roff = (nc >= 128) ? 128 : 0;
    float f0 = W1[(size_t)(roff + k2)     * HIDDEN + col];
    float f1 = W1[(size_t)(roff + k2 + 1) * HIDDEN + col];
    *(unsigned*)(Bt + (size_t)nc * HIDDEN + k2) = (unsigned)f2b(f0) | ((unsigned)f2b(f1) << 16);
}

// ---------------------------------------------------------------------------
// Kernel 1 (MFMA GEMM, persistent): UV = z @ [W1src|W1dst] + [b1|0], bf16 out.
// MEASURED-BEST (R10: 162.0 us wall). Session-verified design rules:
//  - cooperative lane-contiguous staging (1 KB/instr) beats wave-autonomous
//    loads (R8: address divergence -> 2x regression)
//  - no launch_bounds forcing (R6: VGPR 84 -> 60 MB spill writeback)
//  - PC_GRID 512 = exact 2-blocks/CU residency (R10: -5.5 us vs 768)
//  - fused single GEMM beats 2-pass fragment-reorder (R11: +18 us dispatch
//    + round-trip traffic)
// ---------------------------------------------------------------------------
#define AS_STRIDE 136
#define CS_STRIDE 264

__global__ __launch_bounds__(256) void precompute_uv_mfma(
    const float* __restrict__ z, const unsigned short* __restrict__ Bt,
    const float* __restrict__ b1, unsigned short* __restrict__ UV)
{
    __shared__ unsigned short smem[64 * CS_STRIDE];   // 33.8 KB, A and C phases
    const int t = threadIdx.x;
    const int lane = t & 63;
    const int w = t >> 6;
    const int wn = w * 64;
    const int g  = lane >> 4;
    const int lc = lane & 15;

    // --- B fragments + bias: once per block ---
    frag_ab b[4][4];
    float bias[4];
    #pragma unroll
    for (int nt = 0; nt < 4; ++nt) {
        int nc = wn + nt * 16 + lc;
        bias[nt] = (nc < HIDDEN) ? b1[nc] : 0.f;
        const unsigned short* brow = Bt + (size_t)nc * HIDDEN;
        #pragma unroll
        for (int q = 0; q < 4; ++q)
            b[nt][q] = *(const frag_ab*)(brow + q * 32 + g * 8);
    }

    int tile = blockIdx.x;
    uint2 pf[8];   // next A tile, already packed bf16 (16 VGPRs)
    #pragma unroll
    for (int i = 0; i < 8; ++i) {
        int f4 = i * 256 + t;
        int m = tile * 64 + (f4 >> 5);
        if (m >= N_NODES) m = N_NODES - 1;
        float4 v = ((const float4*)z)[(size_t)m * 32 + (f4 & 31)];
        pf[i].x = pk2(v.x, v.y);
        pf[i].y = pk2(v.z, v.w);
    }

    while (true) {
        // --- stage A: packed regs -> LDS ---
        #pragma unroll
        for (int i = 0; i < 8; ++i) {
            int f4 = i * 256 + t;
            *(uint2*)&smem[(f4 >> 5) * AS_STRIDE + (f4 & 31) * 4] = pf[i];
        }
        __syncthreads();

        // --- prefetch NEXT tile (hides HBM latency behind MFMA+epilogue) ---
        const int next = tile + PC_GRID;
        const bool have_next = (next < N_TILES);
        if (have_next) {
            #pragma unroll
            for (int i = 0; i < 8; ++i) {
                int f4 = i * 256 + t;
                int m = next * 64 + (f4 >> 5);
                if (m >= N_NODES) m = N_NODES - 1;
                float4 v = ((const float4*)z)[(size_t)m * 32 + (f4 & 31)];
                pf[i].x = pk2(v.x, v.y);
                pf[i].y = pk2(v.z, v.w);
            }
        }

        // --- K loop: 16 ds_read_b128 + 64 MFMA per wave ---
        frag_cd acc[4][4];
        #pragma unroll
        for (int mt = 0; mt < 4; ++mt)
            #pragma unroll
            for (int nt = 0; nt < 4; ++nt)
                acc[mt][nt] = (frag_cd){0.f, 0.f, 0.f, 0.f};
        #pragma unroll
        for (int q = 0; q < 4; ++q) {
            frag_ab a[4];
            #pragma unroll
            for (int mt = 0; mt < 4; ++mt)
                a[mt] = *(const frag_ab*)&smem[(mt * 16 + lc) * AS_STRIDE + q * 32 + g * 8];
            #pragma unroll
            for (int mt = 0; mt < 4; ++mt)
                #pragma unroll
                for (int nt = 0; nt < 4; ++nt)
                    acc[mt][nt] = __builtin_amdgcn_mfma_f32_16x16x32_bf16(
                        a[mt], b[nt][q], acc[mt][nt], 0, 0, 0);
        }
        __syncthreads();   // A phase over; smem becomes C

        // --- epilogue: acc -> smem (C layout col=lane&15, row=(lane>>4)*4+reg) ---
        #pragma unroll
        for (int nt = 0; nt < 4; ++nt) {
            int nc = wn + nt * 16 + lc;
            #pragma unroll
            for (int mt = 0; mt < 4; ++mt)
                #pragma unroll
                for (int r = 0; r < 4; ++r)
                    smem[(mt * 16 + g * 4 + r) * CS_STRIDE + nc] =
                        f2b(acc[mt][nt][r] + bias[nt]);
        }
        __syncthreads();

        // --- coalesced store: 512 B contiguous per node row ---
        const int m0 = tile * 64;
        #pragma unroll
        for (int i = 0; i < 8; ++i) {
            int f = i * 256 + t;
            int m = f >> 5;
            int c16 = f & 31;
            if (m0 + m < N_NODES) {
                uint4 val = *(const uint4*)&smem[m * CS_STRIDE + c16 * 8];
                *(uint4*)&UV[(size_t)(m0 + m) * 256 + c16 * 8] = val;
            }
        }
        if (!have_next) break;
        __syncthreads();   // C reads done before next stage overwrites
        tile = next;
    }
}

// ---------------------------------------------------------------------------
// Kernel 2: per-edge score = relu(U[src] + V[dst]) . W2 + b2
// At the L2-miss-path gather ceiling (~3.5 TB/s; invariant under 16->8
// lanes/edge, 1->2 edges/thread, 4->8 outstanding loads).
// ---------------------------------------------------------------------------
__device__ inline float2 bf2(unsigned u) {
    union { unsigned i; float f; } lo, hi;
    lo.i = u << 16;
    hi.i = u & 0xffff0000u;
    return make_float2(lo.f, hi.f);
}

__device__ inline float2 rfma2(unsigned u, unsigned v, float2 w, float2 acc) {
    float2 uf = bf2(u), vf = bf2(v);
    float2 s = make_float2(uf.x + vf.x, uf.y + vf.y);
    s.x = fmaxf(s.x, 0.f); s.y = fmaxf(s.y, 0.f);
    acc.x = __builtin_fmaf(s.x, w.x, acc.x);
    acc.y = __builtin_fmaf(s.y, w.y, acc.y);
    return acc;
}

__global__ __launch_bounds__(256) void edge_score(
    const int* __restrict__ ei, const unsigned short* __restrict__ UV,
    const float* __restrict__ W2, const float* __restrict__ B2,
    float* __restrict__ out)
{
    const int t = threadIdx.x;
    const int g = t & 7;
    const int slot = t >> 3;
    const int e0 = blockIdx.x * 64 + slot;
    const int e1 = e0 + 32;

    const float4* W24 = (const float4*)W2;
    const float4 w0 = W24[g * 4 + 0];
    const float4 w1 = W24[g * 4 + 1];
    const float4 w2 = W24[g * 4 + 2];
    const float4 w3 = W24[g * 4 + 3];

    const int s0 = ei[e0];
    const int d0 = ei[N_EDGES + e0];
    const int s1 = ei[e1];
    const int d1 = ei[N_EDGES + e1];

    const uint4* u0p = (const uint4*)(UV + (size_t)s0 * 256) + g * 2;
    const uint4* v0p = (const uint4*)(UV + (size_t)d0 * 256 + 128) + g * 2;
    const uint4* u1p = (const uint4*)(UV + (size_t)s1 * 256) + g * 2;
    const uint4* v1p = (const uint4*)(UV + (size_t)d1 * 256 + 128) + g * 2;
    const uint4 ua0 = u0p[0], ub0 = u0p[1];
    const uint4 va0 = v0p[0], vb0 = v0p[1];
    const uint4 ua1 = u1p[0], ub1 = u1p[1];
    const uint4 va1 = v1p[0], vb1 = v1p[1];

    float2 A = make_float2(0.f, 0.f), B = make_float2(0.f, 0.f);
    A = rfma2(ua0.x, va0.x, make_float2(w0.x, w0.y), A);
    A = rfma2(ua0.y, va0.y, make_float2(w0.z, w0.w), A);
    A = rfma2(ua0.z, va0.z, make_float2(w1.x, w1.y), A);
    A = rfma2(ua0.w, va0.w, make_float2(w1.z, w1.w), A);
    A = rfma2(ub0.x, vb0.x, make_float2(w2.x, w2.y), A);
    A = rfma2(ub0.y, vb0.y, make_float2(w2.z, w2.w), A);
    A = rfma2(ub0.z, vb0.z, make_float2(w3.x, w3.y), A);
    A = rfma2(ub0.w, vb0.w, make_float2(w3.z, w3.w), A);

    B = rfma2(ua1.x, va1.x, make_float2(w0.x, w0.y), B);
    B = rfma2(ua1.y, va1.y, make_float2(w0.z, w0.w), B);
    B = rfma2(ua1.z, va1.z, make_float2(w1.x, w1.y), B);
    B = rfma2(ua1.w, va1.w, make_float2(w1.z, w1.w), B);
    B = rfma2(ub1.x, vb1.x, make_float2(w2.x, w2.y), B);
    B = rfma2(ub1.y, vb1.y, make_float2(w2.z, w2.w), B);
    B = rfma2(ub1.z, vb1.z, make_float2(w3.x, w3.y), B);
    B = rfma2(ub1.w, vb1.w, make_float2(w3.z, w3.w), B);

    float sa = A.x + A.y;
    float sb = B.x + B.y;
    sa += __shfl_xor(sa, 1, 8);
    sa += __shfl_xor(sa, 2, 8);
    sa += __shfl_xor(sa, 4, 8);
    sb += __shfl_xor(sb, 1, 8);
    sb += __shfl_xor(sb, 2, 8);
    sb += __shfl_xor(sb, 4, 8);

    if (g == 0) {
        float bb = B2[0];
        out[e0] = sa + bb;
        out[e1] = sb + bb;
    }
}

extern "C" void kernel_launch(void* const* d_in, const int* in_sizes, int n_in,
                              void* d_out, int out_size, void* d_ws, size_t ws_size,
                              hipStream_t stream) {
    const float* z  = (const float*)d_in[0];
    const int*   ei = (const int*)d_in[1];
    const float* W1 = (const float*)d_in[2];
    const float* b1 = (const float*)d_in[3];
    const float* W2 = (const float*)d_in[4];
    const float* b2 = (const float*)d_in[5];
    float* out = (float*)d_out;

    unsigned short* UV = (unsigned short*)d_ws;                 // 51.2 MB
    unsigned short* Bt = UV + (size_t)N_NODES * 256;            // 64 KB

    transpose_w1<<<64, 256, 0, stream>>>(W1, Bt);
    precompute_uv_mfma<<<PC_GRID, 256, 0, stream>>>(z, Bt, b1, UV);
    edge_score<<<N_EDGES / 64, 256, 0, stream>>>(ei, UV, W2, b2, out);
}